// Round 16
// baseline (327.705 us; speedup 1.0000x reference)
//
#include <hip/hip_runtime.h>
#include <stdint.h>

typedef int v4i  __attribute__((ext_vector_type(4)));
typedef int v16i __attribute__((ext_vector_type(16)));

// ---------------------------------------------------------------------------
// Fused quantize kernel: blocks [0,M) quantize x rows; blocks [M,M+N) pack w
// rows. Both paths are the r1-verified bodies (block-uniform branch).
// ---------------------------------------------------------------------------
__global__ void quant_fused_kernel(const float* __restrict__ x,
                                   const int* __restrict__ w,
                                   int8_t* __restrict__ xq,
                                   int8_t* __restrict__ wq,
                                   int* __restrict__ sum_x,
                                   int* __restrict__ sum_w,
                                   const float* __restrict__ p_scale,
                                   const int* __restrict__ p_zp,
                                   int M, int K) {
    const int t = threadIdx.x;
    const int nchunk = K >> 10;
    int lsum = 0;
    if (blockIdx.x < M) {
        const int row = blockIdx.x;
        const float s = p_scale[0];
        const float zpf = (float)p_zp[0];
        const float* xr = x + (size_t)row * K;
        int8_t* qr = xq + (size_t)row * K;
        for (int i = 0; i < nchunk; ++i) {
            const int idx = (i << 10) + (t << 2);
            const float4 v = *reinterpret_cast<const float4*>(xr + idx);
            const float f0 = fminf(fmaxf(rintf(v.x / s) + zpf, -128.f), 127.f);
            const float f1 = fminf(fmaxf(rintf(v.y / s) + zpf, -128.f), 127.f);
            const float f2 = fminf(fmaxf(rintf(v.z / s) + zpf, -128.f), 127.f);
            const float f3 = fminf(fmaxf(rintf(v.w / s) + zpf, -128.f), 127.f);
            const int i0 = (int)f0, i1 = (int)f1, i2 = (int)f2, i3 = (int)f3;
            lsum += i0 + i1 + i2 + i3;
            const unsigned pk = (unsigned)(i0 & 255) | ((unsigned)(i1 & 255) << 8) |
                                ((unsigned)(i2 & 255) << 16) | ((unsigned)(i3 & 255) << 24);
            *reinterpret_cast<unsigned*>(qr + idx) = pk;
        }
    } else {
        const int row = blockIdx.x - M;
        const int* wr_ = w + (size_t)row * K;
        int8_t* qr = wq + (size_t)row * K;
        for (int i = 0; i < nchunk; ++i) {
            const int idx = (i << 10) + (t << 2);
            const int4 v = *reinterpret_cast<const int4*>(wr_ + idx);
            lsum += v.x + v.y + v.z + v.w;
            const unsigned pk = (unsigned)(v.x & 255) | ((unsigned)(v.y & 255) << 8) |
                                ((unsigned)(v.z & 255) << 16) | ((unsigned)(v.w & 255) << 24);
            *reinterpret_cast<unsigned*>(qr + idx) = pk;
        }
    }
    __shared__ int wsum[4];
    #pragma unroll
    for (int off = 32; off > 0; off >>= 1) lsum += __shfl_down(lsum, off);
    if ((t & 63) == 0) wsum[t >> 6] = lsum;
    __syncthreads();
    if (t == 0) {
        const int tot = wsum[0] + wsum[1] + wsum[2] + wsum[3];
        if (blockIdx.x < M) sum_x[blockIdx.x] = tot;
        else                sum_w[blockIdx.x - M] = tot;
    }
}

// ---------------------------------------------------------------------------
// GEMM: r1's verified reg-staged skeleton (global->VGPR->ds_write, ONE
// __syncthreads per K-tile, compiler-managed waits, NO global_load_lds, NO
// manual vmcnt) with the two defects repaired and occupancy maximized:
//
//  * Fragment-major LDS, LANE-LINEAR both ways: chunk index = fi*64 + lane
//    (fi = ks*4 + rowblock). Thread t writes chunks {t, t+256} -> each wave
//    writes 64 consecutive 16B chunks (sequential banks, conflict-free);
//    reads are chunk base+lane (sequential, conflict-free). r1's 5.03e7
//    write conflicts (~35% of its runtime) -> ~0. No swizzle needed.
//  * 128x128 tile, 4 waves (2x2, wave-tile 64x64), LDS 32 KB, VGPR ~116
//    with launch_bounds(256,4) -> FOUR blocks/CU: 4 independent barrier
//    domains per CU overlap each other's read/latency/sync segments (the
//    28.3 cyc/MFMA lockstep plateau's remaining suspect is the wave-
//    synchronous DMA chain -- absent here entirely).
//
// Race proof (r1 protocol, verified passing): per iter t: head barrier;
// loads(t+1)->regs; reads+MFMA on buf[t&1]; ds_write buf[(t+1)&1]; tail
// barrier(=next head). Writes to a buffer and reads of it are separated by
// that barrier (writes iter t vs reads iter t+1; reads iter t complete
// before the wave's own writes and other waves' writes are after the
// barrier). __syncthreads drains lgkm+vm -> ds_writes visible.
//
// Staging source (thread t, chunks c1=t with fi=t>>6, c2=t+256 with
// fi=4+(t>>6)): row = (t>>6)*32 + (lane&31); c1 kb = (lane>>5)*16;
// c2 kb = 32 + (lane>>5)*16. Invariant: LDS chunk (fi,l) holds global
// [row=(fi&3)*32+(l&31)][kb=(fi>>2)*32+(l>>5)*16] -- same as r1's reads.
// ---------------------------------------------------------------------------
#define BM 128
#define BN 128
#define BKB 64

#define MFMA_I8 __builtin_amdgcn_mfma_i32_32x32x32_i8

__global__ __launch_bounds__(256, 4)
void gemm_i8_kernel(const int8_t* __restrict__ xq,
                    const int8_t* __restrict__ wq,
                    const int* __restrict__ sum_x,
                    const int* __restrict__ sum_w,
                    const float* __restrict__ bias,
                    float* __restrict__ out,
                    const float* __restrict__ p_sa,
                    const int* __restrict__ p_zpa,
                    const float* __restrict__ p_sw,
                    const int* __restrict__ p_wzp,
                    int M, int N, int K) {
    __shared__ v4i ldsA[2][512];    // 2 buf * 8 KB
    __shared__ v4i ldsB[2][512];    // 32 KB total -> 4 blocks/CU

    const int tid = threadIdx.x;    // 256 threads = 4 waves
    const int lane = tid & 63;
    const int wid = tid >> 6;
    const int wr = wid >> 1;        // 0..1: rows wr*64..+63
    const int wc = wid & 1;         // 0..1: cols wc*64..+63

    // XCD-aware bijective swizzle; m-fastest within XCD -> B panel (512KB)
    // L2-resident across the m-sweep.
    const int nwgy = M / BM;                    // 64
    const int nwg = nwgy * (N / BN);            // 2048 (%8==0)
    const int bid = blockIdx.x;
    const int v = (bid & 7) * (nwg >> 3) + (bid >> 3);
    const int m0 = (v % nwgy) * BM;
    const int n0 = (v / nwgy) * BN;

    // ---- staging addresses (lane-linear fragment-major; see header)
    const int srow = wid * 32 + (lane & 31);    // row of both chunks
    const int kb1 = (lane >> 5) << 4;           // chunk t   : ks=0
    const int kb2 = 32 + kb1;                   // chunk t+256: ks=1
    const int8_t* aSrc = xq + (size_t)(m0 + srow) * K;
    const int8_t* bSrc = wq + (size_t)(n0 + srow) * K;

    v16i acc[2][2] = {};
    v4i sA0, sA1, sB0, sB1;                     // staged regs for tile t+1

    const int NT = K / BKB;                     // 64

    // ---- prologue: tile 0 -> regs -> LDS buf 0; publish.
    sA0 = *reinterpret_cast<const v4i*>(aSrc + kb1);
    sA1 = *reinterpret_cast<const v4i*>(aSrc + kb2);
    sB0 = *reinterpret_cast<const v4i*>(bSrc + kb1);
    sB1 = *reinterpret_cast<const v4i*>(bSrc + kb2);
    ldsA[0][tid] = sA0; ldsA[0][tid + 256] = sA1;
    ldsB[0][tid] = sB0; ldsB[0][tid + 256] = sB1;
    __syncthreads();

    for (int t = 0; t < NT; ++t) {
        const int cur = t & 1;
        // issue next tile's global loads (compiler hoists; vmcnt before write)
        if (t + 1 < NT) {
            const int koff = (t + 1) * BKB;
            sA0 = *reinterpret_cast<const v4i*>(aSrc + koff + kb1);
            sA1 = *reinterpret_cast<const v4i*>(aSrc + koff + kb2);
            sB0 = *reinterpret_cast<const v4i*>(bSrc + koff + kb1);
            sB1 = *reinterpret_cast<const v4i*>(bSrc + koff + kb2);
        }
        // fragment reads (lane-linear, conflict-free) + MFMA
        __builtin_amdgcn_s_setprio(1);
        #pragma unroll
        for (int ks = 0; ks < 2; ++ks) {
            const v4i a0 = ldsA[cur][(ks * 4 + wr * 2 + 0) * 64 + lane];
            const v4i a1 = ldsA[cur][(ks * 4 + wr * 2 + 1) * 64 + lane];
            const v4i b0 = ldsB[cur][(ks * 4 + wc * 2 + 0) * 64 + lane];
            const v4i b1 = ldsB[cur][(ks * 4 + wc * 2 + 1) * 64 + lane];
            acc[0][0] = MFMA_I8(a0, b0, acc[0][0], 0, 0, 0);
            acc[0][1] = MFMA_I8(a0, b1, acc[0][1], 0, 0, 0);
            acc[1][0] = MFMA_I8(a1, b0, acc[1][0], 0, 0, 0);
            acc[1][1] = MFMA_I8(a1, b1, acc[1][1], 0, 0, 0);
        }
        __builtin_amdgcn_s_setprio(0);
        // lane-linear ds_write of tile t+1 into the other buffer
        if (t + 1 < NT) {
            const int nb = cur ^ 1;
            ldsA[nb][tid] = sA0; ldsA[nb][tid + 256] = sA1;
            ldsB[nb][tid] = sB0; ldsB[nb][tid + 256] = sB1;
        }
        __syncthreads();
    }

    // ---- epilogue (r1-verified): y = (acc - wzp*sx - zp*sw + K*zp*wzp)*s + b
    const float stot = p_sa[0] * p_sw[0];
    const int zpa = p_zpa[0];
    const int wzp = p_wzp[0];
    const int kzz = K * zpa * wzp;
    const int coll = lane & 31;
    const int rhi = (lane >> 5) * 4;

    #pragma unroll
    for (int nf = 0; nf < 2; ++nf) {
        const int cg = n0 + wc * 64 + nf * 32 + coll;
        const int sw = sum_w[cg];
        const float bb = bias[cg];
        #pragma unroll
        for (int mf = 0; mf < 2; ++mf) {
            const int rbase = m0 + wr * 64 + mf * 32 + rhi;
            #pragma unroll
            for (int r = 0; r < 16; ++r) {
                const int rowg = rbase + (r & 3) + 8 * (r >> 2);
                const int iv = acc[mf][nf][r] - wzp * sum_x[rowg] - zpa * sw + kzz;
                out[(size_t)rowg * N + cg] = (float)iv * stot + bb;
            }
        }
    }
}

// ---------------------------------------------------------------------------
extern "C" void kernel_launch(void* const* d_in, const int* in_sizes, int n_in,
                              void* d_out, int out_size, void* d_ws, size_t ws_size,
                              hipStream_t stream) {
    const float* x     = (const float*)d_in[0];
    const int*   w     = (const int*)d_in[1];
    const float* bias  = (const float*)d_in[2];
    const float* p_sa  = (const float*)d_in[3];
    const int*   p_zpa = (const int*)d_in[4];
    const float* p_sw  = (const float*)d_in[5];
    const int*   p_wzp = (const int*)d_in[6];

    const int N = in_sizes[2];             // OUT
    const int K = in_sizes[1] / N;         // IN
    const int M = in_sizes[0] / K;         // B*S

    int8_t* xq = (int8_t*)d_ws;
    int8_t* wq = xq + (size_t)M * K;
    int* sum_x = (int*)(wq + (size_t)N * K);
    int* sum_w = sum_x + M;

    quant_fused_kernel<<<M + N, 256, 0, stream>>>(x, w, xq, wq, sum_x, sum_w,
                                                  p_sa, p_zpa, M, K);

    const int nwg = (M / BM) * (N / BN);   // 2048
    gemm_i8_kernel<<<nwg, 256, 0, stream>>>(xq, wq, sum_x, sum_w, bias,
                                            (float*)d_out, p_sa, p_zpa, p_sw, p_wzp,
                                            M, N, K);
}

// Round 17
// 235.963 us; speedup vs baseline: 1.3888x; 1.3888x over previous
//
#include <hip/hip_runtime.h>
#include <stdint.h>

typedef int v4i  __attribute__((ext_vector_type(4)));
typedef int v16i __attribute__((ext_vector_type(16)));

// ---------------------------------------------------------------------------
// Fused quantize kernel (r16-verified): blocks [0,M) quantize x rows;
// blocks [M,M+N) pack w rows. One launch -> x-path and w-path run
// CONCURRENTLY across CUs (r4's serial pair cost ~47us; fused ~15us).
// ---------------------------------------------------------------------------
__global__ void quant_fused_kernel(const float* __restrict__ x,
                                   const int* __restrict__ w,
                                   int8_t* __restrict__ xq,
                                   int8_t* __restrict__ wq,
                                   int* __restrict__ sum_x,
                                   int* __restrict__ sum_w,
                                   const float* __restrict__ p_scale,
                                   const int* __restrict__ p_zp,
                                   int M, int K) {
    const int t = threadIdx.x;
    const int nchunk = K >> 10;
    int lsum = 0;
    if (blockIdx.x < M) {
        const int row = blockIdx.x;
        const float s = p_scale[0];
        const float zpf = (float)p_zp[0];
        const float* xr = x + (size_t)row * K;
        int8_t* qr = xq + (size_t)row * K;
        for (int i = 0; i < nchunk; ++i) {
            const int idx = (i << 10) + (t << 2);
            const float4 v = *reinterpret_cast<const float4*>(xr + idx);
            const float f0 = fminf(fmaxf(rintf(v.x / s) + zpf, -128.f), 127.f);
            const float f1 = fminf(fmaxf(rintf(v.y / s) + zpf, -128.f), 127.f);
            const float f2 = fminf(fmaxf(rintf(v.z / s) + zpf, -128.f), 127.f);
            const float f3 = fminf(fmaxf(rintf(v.w / s) + zpf, -128.f), 127.f);
            const int i0 = (int)f0, i1 = (int)f1, i2 = (int)f2, i3 = (int)f3;
            lsum += i0 + i1 + i2 + i3;
            const unsigned pk = (unsigned)(i0 & 255) | ((unsigned)(i1 & 255) << 8) |
                                ((unsigned)(i2 & 255) << 16) | ((unsigned)(i3 & 255) << 24);
            *reinterpret_cast<unsigned*>(qr + idx) = pk;
        }
    } else {
        const int row = blockIdx.x - M;
        const int* wr_ = w + (size_t)row * K;
        int8_t* qr = wq + (size_t)row * K;
        for (int i = 0; i < nchunk; ++i) {
            const int idx = (i << 10) + (t << 2);
            const int4 v = *reinterpret_cast<const int4*>(wr_ + idx);
            lsum += v.x + v.y + v.z + v.w;
            const unsigned pk = (unsigned)(v.x & 255) | ((unsigned)(v.y & 255) << 8) |
                                ((unsigned)(v.z & 255) << 16) | ((unsigned)(v.w & 255) << 24);
            *reinterpret_cast<unsigned*>(qr + idx) = pk;
        }
    }
    __shared__ int wsum[4];
    #pragma unroll
    for (int off = 32; off > 0; off >>= 1) lsum += __shfl_down(lsum, off);
    if ((t & 63) == 0) wsum[t >> 6] = lsum;
    __syncthreads();
    if (t == 0) {
        const int tot = wsum[0] + wsum[1] + wsum[2] + wsum[3];
        if (blockIdx.x < M) sum_x[blockIdx.x] = tot;
        else                sum_w[blockIdx.x - M] = tot;
    }
}

// ---------------------------------------------------------------------------
// GEMM (r10-verified, best family member): 256x256 tile, 4 waves (2x2),
// wave-tile 128x128, pure-DMA 4-slot pipeline, distance-2 prefetch, ONE
// barrier + ONE counted vmcnt(8) per K-tile.
//
// Plateau characterization (r4..r16 matrix, all >=192us / 28.3 cyc/MFMA):
// not LDS BW (r10 halved reads: no change), not bank conflicts (r11 zeroed:
// no change), not barrier count (r10 1/tile: no change), not occupancy
// (r14 2 blocks/CU: no change), not the DMA engine per se (r16 reg-staged:
// worse via lost arithmetic intensity). Residual: per-phase latency
// convergence of lockstep waves. 31% of the 4404-TOPS i8 ceiling is this
// structure's measured bound; MFMA-only floor would be 62us.
//
// Slot safety: data for tile t staged at t-2; per-wave vmcnt(8) at end of
// t-1 retires its t-staging (pure in-order DMA stream); barrier publishes.
// WAR: slot (t+2)&3 overwritten at tile t, last read t-2, >=2 barriers
// earlier. Swizzle (r6-verified): stored chunk' = chunk ^ f(row),
// f(row)=((row>>1)^(row>>3))&3; linear DMA dest, inverse-swizzled source.
// ---------------------------------------------------------------------------
#define BM 256
#define BN 256
#define BKB 64
#define NSLOT 4

__device__ __forceinline__ void gload_lds16(const void* g, void* l) {
    __builtin_amdgcn_global_load_lds(
        (const __attribute__((address_space(1))) unsigned int*)g,
        (__attribute__((address_space(3))) unsigned int*)l, 16, 0, 0);
}

#define MFMA_I8 __builtin_amdgcn_mfma_i32_32x32x32_i8

__global__ __launch_bounds__(256, 1)
void gemm_i8_kernel(const int8_t* __restrict__ xq,
                    const int8_t* __restrict__ wq,
                    const int* __restrict__ sum_x,
                    const int* __restrict__ sum_w,
                    const float* __restrict__ bias,
                    float* __restrict__ out,
                    const float* __restrict__ p_sa,
                    const int* __restrict__ p_zpa,
                    const float* __restrict__ p_sw,
                    const int* __restrict__ p_wzp,
                    int M, int N, int K) {
    __shared__ v4i ldsA[NSLOT][1024];   // 4 slots * 16KB = 64 KiB
    __shared__ v4i ldsB[NSLOT][1024];   // 128 KiB total

    const int tid = threadIdx.x;        // 256 threads = 4 waves
    const int lane = tid & 63;
    const int wid = tid >> 6;
    const int wr = wid >> 1;            // 0..1: rows wr*128..+127
    const int wc = wid & 1;             // 0..1: cols wc*128..+127

    // XCD-aware bijective swizzle (nwg = 512, %8 == 0)
    const int nwgy = M / BM;
    const int nwg = nwgy * (N / BN);
    const int bid = blockIdx.x;
    const int v = (bid & 7) * (nwg >> 3) + (bid >> 3);
    const int m0 = (v % nwgy) * BM;
    const int n0 = (v / nwgy) * BN;

    // ---- staging: thread tid handles chunks {tid + k*256, k=0..3} per
    // operand per tile. chunk p: row = p>>2, stored chunk' = p&3.
    // srow = tid>>2 (0..63); row = srow + k*64 (f(row) independent of k).
    const int srow = tid >> 2;
    const int schunk = (tid & 3) ^ (((srow >> 1) ^ (srow >> 3)) & 3);
    const int8_t* aS = xq + (size_t)(m0 + srow) * K + schunk * 16;
    const int8_t* bS = wq + (size_t)(n0 + srow) * K + schunk * 16;
    const size_t qtr = (size_t)64 * K;                  // +64 rows
    const int dbase = wid * 64;                         // wave-uniform

    // ---- fragment reads: row = (wr|wc)*128 + f_idx*32 + (lane&31),
    // logical chunk c = ks*2 + (lane>>5); stored at c ^ f(row).
    const int sel = ((lane >> 1) ^ (lane >> 3)) & 3;
    const int hi = lane >> 5;
    const int c0 = hi ^ sel;            // ks0 stored chunk
    const int c1 = (2 + hi) ^ sel;      // ks1 stored chunk
    int arow[4], brow[4];
    #pragma unroll
    for (int i = 0; i < 4; ++i) {
        arow[i] = (wr * 128 + i * 32 + (lane & 31)) * 4;
        brow[i] = (wc * 128 + i * 32 + (lane & 31)) * 4;
    }

    v16i acc[4][4] = {};
    const int NT = K / BKB;             // 64

#define STAGE(SLOT, T_) do {                                                  \
        const int8_t* pa_ = aS + (size_t)(T_) * BKB;                          \
        const int8_t* pb_ = bS + (size_t)(T_) * BKB;                          \
        _Pragma("unroll")                                                     \
        for (int k_ = 0; k_ < 4; ++k_) {                                      \
            gload_lds16(pa_ + k_ * qtr, &ldsA[SLOT][k_ * 256 + dbase]);       \
            gload_lds16(pb_ + k_ * qtr, &ldsB[SLOT][k_ * 256 + dbase]);       \
        }                                                                     \
    } while (0)

    // ---- prologue: stage tiles 0 and 1 (8 DMA each)
    STAGE(0, 0);
    STAGE(1, 1);
    asm volatile("s_waitcnt vmcnt(8)" ::: "memory");   // tile 0 landed
    __builtin_amdgcn_sched_barrier(0);
    __builtin_amdgcn_s_barrier();

    for (int t = 0; t < NT; ++t) {
        const v4i* LA = ldsA[t & 3];
        const v4i* LB = ldsB[t & 3];
        v4i a[4][2], b[4][2];
        #pragma unroll
        for (int i = 0; i < 4; ++i) {
            a[i][0] = LA[arow[i] + c0];
            a[i][1] = LA[arow[i] + c1];
        }
        #pragma unroll
        for (int i = 0; i < 4; ++i) {
            b[i][0] = LB[brow[i] + c0];
            b[i][1] = LB[brow[i] + c1];
        }
        if (t + 2 < NT) STAGE((t + 2) & 3, t + 2);
        __builtin_amdgcn_s_setprio(1);
        #pragma unroll
        for (int ks = 0; ks < 2; ++ks)
            #pragma unroll
            for (int rf = 0; rf < 4; ++rf)
                #pragma unroll
                for (int cf = 0; cf < 4; ++cf)
                    acc[rf][cf] = MFMA_I8(a[rf][ks], b[cf][ks], acc[rf][cf], 0, 0, 0);
        __builtin_amdgcn_s_setprio(0);
        // counted wait on the PURE DMA stream: this tile issued 8 (t+2);
        // waiting to 8 retires tile t+1's stages (in-order; r3-r6/r10
        // verified semantics).
        if (t + 2 < NT) {
            asm volatile("s_waitcnt vmcnt(8)" ::: "memory");
        } else if (t + 1 < NT) {
            asm volatile("s_waitcnt vmcnt(0)" ::: "memory");
        }
        __builtin_amdgcn_sched_barrier(0);
        __builtin_amdgcn_s_barrier();
    }
#undef STAGE

    // ---- epilogue: y = (acc - wzp*sum_x[m] - zp*sum_w[n] + K*zp*wzp)*(sa*sw) + bias[n]
    const float stot = p_sa[0] * p_sw[0];
    const int zpa = p_zpa[0];
    const int wzp = p_wzp[0];
    const int kzz = K * zpa * wzp;
    const int coll = lane & 31;
    const int rhi = (lane >> 5) * 4;

    #pragma unroll
    for (int cf = 0; cf < 4; ++cf) {
        const int cg = n0 + wc * 128 + cf * 32 + coll;
        const int sw = sum_w[cg];
        const float bb = bias[cg];
        #pragma unroll
        for (int rf = 0; rf < 4; ++rf) {
            const int rbase = m0 + wr * 128 + rf * 32 + rhi;
            #pragma unroll
            for (int r = 0; r < 16; ++r) {
                const int rowg = rbase + (r & 3) + 8 * (r >> 2);
                const int iv = acc[rf][cf][r] - wzp * sum_x[rowg] - zpa * sw + kzz;
                out[(size_t)rowg * N + cg] = (float)iv * stot + bb;
            }
        }
    }
}

// ---------------------------------------------------------------------------
extern "C" void kernel_launch(void* const* d_in, const int* in_sizes, int n_in,
                              void* d_out, int out_size, void* d_ws, size_t ws_size,
                              hipStream_t stream) {
    const float* x     = (const float*)d_in[0];
    const int*   w     = (const int*)d_in[1];
    const float* bias  = (const float*)d_in[2];
    const float* p_sa  = (const float*)d_in[3];
    const int*   p_zpa = (const int*)d_in[4];
    const float* p_sw  = (const float*)d_in[5];
    const int*   p_wzp = (const int*)d_in[6];

    const int N = in_sizes[2];             // OUT
    const int K = in_sizes[1] / N;         // IN
    const int M = in_sizes[0] / K;         // B*S

    int8_t* xq = (int8_t*)d_ws;
    int8_t* wq = xq + (size_t)M * K;
    int* sum_x = (int*)(wq + (size_t)N * K);
    int* sum_w = sum_x + M;

    quant_fused_kernel<<<M + N, 256, 0, stream>>>(x, w, xq, wq, sum_x, sum_w,
                                                  p_sa, p_zpa, M, K);

    const int nwg = (M / BM) * (N / BN);   // 512
    gemm_i8_kernel<<<nwg, 256, 0, stream>>>(xq, wq, sum_x, sum_w, bias,
                                            (float*)d_out, p_sa, p_zpa, p_sw, p_wzp,
                                            M, N, K);
}

// Round 18
// 228.577 us; speedup vs baseline: 1.4337x; 1.0323x over previous
//
#include <hip/hip_runtime.h>
#include <stdint.h>

typedef int v4i  __attribute__((ext_vector_type(4)));
typedef int v16i __attribute__((ext_vector_type(16)));

// ---------------------------------------------------------------------------
// Fused quantize kernel (r16/r17-verified): blocks [0,M) quantize x rows;
// blocks [M,M+N) pack w rows; one launch, paths run concurrently.
// ---------------------------------------------------------------------------
__global__ void quant_fused_kernel(const float* __restrict__ x,
                                   const int* __restrict__ w,
                                   int8_t* __restrict__ xq,
                                   int8_t* __restrict__ wq,
                                   int* __restrict__ sum_x,
                                   int* __restrict__ sum_w,
                                   const float* __restrict__ p_scale,
                                   const int* __restrict__ p_zp,
                                   int M, int K) {
    const int t = threadIdx.x;
    const int nchunk = K >> 10;
    int lsum = 0;
    if (blockIdx.x < M) {
        const int row = blockIdx.x;
        const float s = p_scale[0];
        const float zpf = (float)p_zp[0];
        const float* xr = x + (size_t)row * K;
        int8_t* qr = xq + (size_t)row * K;
        for (int i = 0; i < nchunk; ++i) {
            const int idx = (i << 10) + (t << 2);
            const float4 v = *reinterpret_cast<const float4*>(xr + idx);
            const float f0 = fminf(fmaxf(rintf(v.x / s) + zpf, -128.f), 127.f);
            const float f1 = fminf(fmaxf(rintf(v.y / s) + zpf, -128.f), 127.f);
            const float f2 = fminf(fmaxf(rintf(v.z / s) + zpf, -128.f), 127.f);
            const float f3 = fminf(fmaxf(rintf(v.w / s) + zpf, -128.f), 127.f);
            const int i0 = (int)f0, i1 = (int)f1, i2 = (int)f2, i3 = (int)f3;
            lsum += i0 + i1 + i2 + i3;
            const unsigned pk = (unsigned)(i0 & 255) | ((unsigned)(i1 & 255) << 8) |
                                ((unsigned)(i2 & 255) << 16) | ((unsigned)(i3 & 255) << 24);
            *reinterpret_cast<unsigned*>(qr + idx) = pk;
        }
    } else {
        const int row = blockIdx.x - M;
        const int* wr_ = w + (size_t)row * K;
        int8_t* qr = wq + (size_t)row * K;
        for (int i = 0; i < nchunk; ++i) {
            const int idx = (i << 10) + (t << 2);
            const int4 v = *reinterpret_cast<const int4*>(wr_ + idx);
            lsum += v.x + v.y + v.z + v.w;
            const unsigned pk = (unsigned)(v.x & 255) | ((unsigned)(v.y & 255) << 8) |
                                ((unsigned)(v.z & 255) << 16) | ((unsigned)(v.w & 255) << 24);
            *reinterpret_cast<unsigned*>(qr + idx) = pk;
        }
    }
    __shared__ int wsum[4];
    #pragma unroll
    for (int off = 32; off > 0; off >>= 1) lsum += __shfl_down(lsum, off);
    if ((t & 63) == 0) wsum[t >> 6] = lsum;
    __syncthreads();
    if (t == 0) {
        const int tot = wsum[0] + wsum[1] + wsum[2] + wsum[3];
        if (blockIdx.x < M) sum_x[blockIdx.x] = tot;
        else                sum_w[blockIdx.x - M] = tot;
    }
}

// ---------------------------------------------------------------------------
// GEMM == r17 verbatim (r10-verified structure: 256x256 tile, 4 waves 2x2,
// wave-tile 128x128, pure-DMA 4-slot pipeline, distance-2 prefetch, one
// barrier + one counted vmcnt(8) per K-tile) with ONE change:
//
// XCD-L2-RESIDENT BLOCK ORDER. r17's decode was m-fastest: each XCD swept
// the full 32MB A per n-panel -> A thrashes XCD-L2 (4MB) and the 131MB C
// write-stream flushes L3 -> FETCH 271MB vs ~48MB ideal; ~900cyc HBM-miss
// latency lands inside the lockstep tile loop (the unexplained ~1700
// cyc/tile). New decode: each XCD OWNS an M-stripe of nwgy/8 = 4 m-tiles
// (1024 rows = 4MB of A = exactly one XCD-L2) and sweeps n fastest:
//     xcd = bid&7 ; loc = bid>>3 ; mt = xcd*(nwgy/8) + loc/nwgx ;
//     nt = loc%nwgx          (bijective for nwgy%8==0; inverse checked)
// A re-reads now hit the XCD's own L2; B (16MB) streams once per XCD from
// L3. Everything else (staging, swizzle, sync, epilogue) byte-identical.
// ---------------------------------------------------------------------------
#define BM 256
#define BN 256
#define BKB 64
#define NSLOT 4

__device__ __forceinline__ void gload_lds16(const void* g, void* l) {
    __builtin_amdgcn_global_load_lds(
        (const __attribute__((address_space(1))) unsigned int*)g,
        (__attribute__((address_space(3))) unsigned int*)l, 16, 0, 0);
}

#define MFMA_I8 __builtin_amdgcn_mfma_i32_32x32x32_i8

__global__ __launch_bounds__(256, 1)
void gemm_i8_kernel(const int8_t* __restrict__ xq,
                    const int8_t* __restrict__ wq,
                    const int* __restrict__ sum_x,
                    const int* __restrict__ sum_w,
                    const float* __restrict__ bias,
                    float* __restrict__ out,
                    const float* __restrict__ p_sa,
                    const int* __restrict__ p_zpa,
                    const float* __restrict__ p_sw,
                    const int* __restrict__ p_wzp,
                    int M, int N, int K) {
    __shared__ v4i ldsA[NSLOT][1024];   // 4 slots * 16KB = 64 KiB
    __shared__ v4i ldsB[NSLOT][1024];   // 128 KiB total

    const int tid = threadIdx.x;        // 256 threads = 4 waves
    const int lane = tid & 63;
    const int wid = tid >> 6;
    const int wr = wid >> 1;            // 0..1: rows wr*128..+127
    const int wc = wid & 1;             // 0..1: cols wc*128..+127

    // XCD-L2-resident decode: XCD owns an M-stripe, sweeps n fastest.
    const int nwgy = M / BM;            // 32
    const int nwgx = N / BN;            // 16
    const int spx = nwgy >> 3;          // m-tiles per XCD stripe (4)
    const int bid = blockIdx.x;
    const int xcd = bid & 7;
    const int loc = bid >> 3;           // 0 .. spx*nwgx-1
    const int m0 = (xcd * spx + loc / nwgx) * BM;
    const int n0 = (loc % nwgx) * BN;

    // ---- staging: thread tid handles chunks {tid + k*256, k=0..3} per
    // operand per tile. chunk p: row = p>>2, stored chunk' = p&3.
    // srow = tid>>2 (0..63); row = srow + k*64 (f(row) independent of k).
    const int srow = tid >> 2;
    const int schunk = (tid & 3) ^ (((srow >> 1) ^ (srow >> 3)) & 3);
    const int8_t* aS = xq + (size_t)(m0 + srow) * K + schunk * 16;
    const int8_t* bS = wq + (size_t)(n0 + srow) * K + schunk * 16;
    const size_t qtr = (size_t)64 * K;                  // +64 rows
    const int dbase = wid * 64;                         // wave-uniform

    // ---- fragment reads: row = (wr|wc)*128 + f_idx*32 + (lane&31),
    // logical chunk c = ks*2 + (lane>>5); stored at c ^ f(row).
    const int sel = ((lane >> 1) ^ (lane >> 3)) & 3;
    const int hi = lane >> 5;
    const int c0 = hi ^ sel;            // ks0 stored chunk
    const int c1 = (2 + hi) ^ sel;      // ks1 stored chunk
    int arow[4], brow[4];
    #pragma unroll
    for (int i = 0; i < 4; ++i) {
        arow[i] = (wr * 128 + i * 32 + (lane & 31)) * 4;
        brow[i] = (wc * 128 + i * 32 + (lane & 31)) * 4;
    }

    v16i acc[4][4] = {};
    const int NT = K / BKB;             // 64

#define STAGE(SLOT, T_) do {                                                  \
        const int8_t* pa_ = aS + (size_t)(T_) * BKB;                          \
        const int8_t* pb_ = bS + (size_t)(T_) * BKB;                          \
        _Pragma("unroll")                                                     \
        for (int k_ = 0; k_ < 4; ++k_) {                                      \
            gload_lds16(pa_ + k_ * qtr, &ldsA[SLOT][k_ * 256 + dbase]);       \
            gload_lds16(pb_ + k_ * qtr, &ldsB[SLOT][k_ * 256 + dbase]);       \
        }                                                                     \
    } while (0)

    // ---- prologue: stage tiles 0 and 1 (8 DMA each)
    STAGE(0, 0);
    STAGE(1, 1);
    asm volatile("s_waitcnt vmcnt(8)" ::: "memory");   // tile 0 landed
    __builtin_amdgcn_sched_barrier(0);
    __builtin_amdgcn_s_barrier();

    for (int t = 0; t < NT; ++t) {
        const v4i* LA = ldsA[t & 3];
        const v4i* LB = ldsB[t & 3];
        v4i a[4][2], b[4][2];
        #pragma unroll
        for (int i = 0; i < 4; ++i) {
            a[i][0] = LA[arow[i] + c0];
            a[i][1] = LA[arow[i] + c1];
        }
        #pragma unroll
        for (int i = 0; i < 4; ++i) {
            b[i][0] = LB[brow[i] + c0];
            b[i][1] = LB[brow[i] + c1];
        }
        if (t + 2 < NT) STAGE((t + 2) & 3, t + 2);
        __builtin_amdgcn_s_setprio(1);
        #pragma unroll
        for (int ks = 0; ks < 2; ++ks)
            #pragma unroll
            for (int rf = 0; rf < 4; ++rf)
                #pragma unroll
                for (int cf = 0; cf < 4; ++cf)
                    acc[rf][cf] = MFMA_I8(a[rf][ks], b[cf][ks], acc[rf][cf], 0, 0, 0);
        __builtin_amdgcn_s_setprio(0);
        // counted wait on the PURE DMA stream: this tile issued 8 (t+2);
        // waiting to 8 retires tile t+1's stages (in-order; r3-r6/r10/r17
        // verified semantics).
        if (t + 2 < NT) {
            asm volatile("s_waitcnt vmcnt(8)" ::: "memory");
        } else if (t + 1 < NT) {
            asm volatile("s_waitcnt vmcnt(0)" ::: "memory");
        }
        __builtin_amdgcn_sched_barrier(0);
        __builtin_amdgcn_s_barrier();
    }
#undef STAGE

    // ---- epilogue: y = (acc - wzp*sum_x[m] - zp*sum_w[n] + K*zp*wzp)*(sa*sw) + bias[n]
    const float stot = p_sa[0] * p_sw[0];
    const int zpa = p_zpa[0];
    const int wzp = p_wzp[0];
    const int kzz = K * zpa * wzp;
    const int coll = lane & 31;
    const int rhi = (lane >> 5) * 4;

    #pragma unroll
    for (int cf = 0; cf < 4; ++cf) {
        const int cg = n0 + wc * 128 + cf * 32 + coll;
        const int sw = sum_w[cg];
        const float bb = bias[cg];
        #pragma unroll
        for (int rf = 0; rf < 4; ++rf) {
            const int rbase = m0 + wr * 128 + rf * 32 + rhi;
            #pragma unroll
            for (int r = 0; r < 16; ++r) {
                const int rowg = rbase + (r & 3) + 8 * (r >> 2);
                const int iv = acc[rf][cf][r] - wzp * sum_x[rowg] - zpa * sw + kzz;
                out[(size_t)rowg * N + cg] = (float)iv * stot + bb;
            }
        }
    }
}

// ---------------------------------------------------------------------------
extern "C" void kernel_launch(void* const* d_in, const int* in_sizes, int n_in,
                              void* d_out, int out_size, void* d_ws, size_t ws_size,
                              hipStream_t stream) {
    const float* x     = (const float*)d_in[0];
    const int*   w     = (const int*)d_in[1];
    const float* bias  = (const float*)d_in[2];
    const float* p_sa  = (const float*)d_in[3];
    const int*   p_zpa = (const int*)d_in[4];
    const float* p_sw  = (const float*)d_in[5];
    const int*   p_wzp = (const int*)d_in[6];

    const int N = in_sizes[2];             // OUT
    const int K = in_sizes[1] / N;         // IN
    const int M = in_sizes[0] / K;         // B*S

    int8_t* xq = (int8_t*)d_ws;
    int8_t* wq = xq + (size_t)M * K;
    int* sum_x = (int*)(wq + (size_t)N * K);
    int* sum_w = sum_x + M;

    quant_fused_kernel<<<M + N, 256, 0, stream>>>(x, w, xq, wq, sum_x, sum_w,
                                                  p_sa, p_zpa, M, K);

    const int nwg = (M / BM) * (N / BN);   // 512
    gemm_i8_kernel<<<nwg, 256, 0, stream>>>(xq, wq, sum_x, sum_w, bias,
                                            (float*)d_out, p_sa, p_zpa, p_sw, p_wzp,
                                            M, N, K);
}